// Round 6
// baseline (146.559 us; speedup 1.0000x reference)
//
#include <hip/hip_runtime.h>
#include <hip/hip_bf16.h>

// Problem constants
#define NT 8192            // tokens
#define NQB 6              // qubits
#define NL 2               // layers
// Attention kernel tiling
#define JSPLIT 16
#define JSLICE (NT / JSPLIT)     // 512 keys per block
#define IPW 32                   // query rows per wave (2 rowtiles of 16)
#define WPB 4                    // waves per block
#define IPB (IPW * WPB)          // 128 rows per block
#define NBI (NT / IPB)           // 64 i-blocks
#define NCT (JSLICE / 16)        // 32 key-tiles of 16 per block

typedef __bf16 bf16x8 __attribute__((ext_vector_type(8)));
typedef float f32x4 __attribute__((ext_vector_type(4)));

static __device__ __forceinline__ unsigned int pack_bf2(float a, float b) {
  unsigned short lo = __builtin_bit_cast(unsigned short, __float2bfloat16(a));
  unsigned short hi = __builtin_bit_cast(unsigned short, __float2bfloat16(b));
  return (unsigned int)lo | ((unsigned int)hi << 16);
}

// one CNOT's index map: src(p) = p ^ (bit_c(p) ? mask_t : 0)  (an involution)
static __device__ __forceinline__ int cnot_src(int p, int q) {
  const int mc = 1 << (5 - q);
  const int mt = 1 << (5 - ((q + 1) % NQB));
  return (p & mc) ? (p ^ mt) : p;
}

// ---------------------------------------------------------------------------
// Kernel 1: statevector prep, product-state form (verified r3-r5).
// One wave per (token, set); lane = basis state.
// ---------------------------------------------------------------------------
__global__ __launch_bounds__(256) void prep_kernel(
    const float* __restrict__ x, const float* __restrict__ pq,
    const float* __restrict__ pk, const float* __restrict__ pv,
    unsigned int* __restrict__ Are, unsigned int* __restrict__ Bk,
    float4* __restrict__ V4)
{
  const int wid  = blockIdx.x * 4 + (threadIdx.x >> 6);
  const int lane = threadIdx.x & 63;
  const int set  = wid >> 13;          // / 8192
  const int tok  = wid & (NT - 1);
  const float* pp = (set == 0) ? pq : ((set == 1) ? pk : pv);

  // sigma(l) = src_0(src_1(...src_5(l)))   [final[l] = old[sigma(l)]]
  int m = lane;
#pragma unroll
  for (int q = 5; q >= 0; --q) m = cnot_src(m, q);
  // sigma^{-1}(l) = src_5(src_4(...src_0(l)))
  int inv = lane;
#pragma unroll
  for (int q = 0; q < 6; ++q) inv = cnot_src(inv, q);

  // product state (through layer-0) evaluated at index m
  float R = 1.f, phi = 0.f;
#pragma unroll
  for (int q = 0; q < 6; ++q) {
    const float t = 0.5f * (x[tok * NQB + q] + pp[q * 2 + 0]);
    const float s = __sinf(t), c = __cosf(t);
    const float bh = 0.5f * pp[q * 2 + 1];
    if ((m >> (5 - q)) & 1) { R *= s; phi += bh; }
    else                    { R *= c; phi -= bh; }
  }
  float re = R * __cosf(phi), im = R * __sinf(phi);

  // layer-1 RYs (entangled now -> shuffles)
#pragma unroll
  for (int q = 0; q < 6; ++q) {
    const int mask = 1 << (5 - q);
    const float t = 0.5f * pp[2 * NQB + q * 2 + 0];
    const float s = __sinf(t), c = __cosf(t);
    const float pre = __shfl_xor(re, mask, 64);
    const float pim = __shfl_xor(im, mask, 64);
    const float se = (lane & mask) ? s : -s;
    re = fmaf(se, pre, c * re);
    im = fmaf(se, pim, c * im);
  }
  // layer-1 RZs combined into one phase per lane
  float phi2 = 0.f;
#pragma unroll
  for (int q = 0; q < 6; ++q) {
    const float bh = 0.5f * pp[2 * NQB + q * 2 + 1];
    phi2 += (lane & (1 << (5 - q))) ? bh : -bh;
  }
  const float s2 = __sinf(phi2), c2 = __cosf(phi2);
  const float fre = re * c2 - im * s2;
  const float fim = re * s2 + im * c2;

  if (set == 0) {
    Are[tok * 64 + inv] = pack_bf2(fre, fim);     // [qr, qi]
  } else if (set == 1) {
    Bk[tok * 64 + inv] = pack_bf2(fre, fim);      // [kr, ki]
  } else {
    const float prob = fre * fre + fim * fim;     // prob of final basis index 'inv'
    float vq[NQB];
#pragma unroll
    for (int q = 0; q < NQB; ++q) {
      float v = (inv & (1 << (5 - q))) ? -prob : prob;  // sign = 1-2*bit
#pragma unroll
      for (int off = 1; off < 64; off <<= 1) v += __shfl_xor(v, off, 64);
      vq[q] = v;
    }
    if (lane == 0) {
      V4[tok * 2 + 0] = make_float4(vq[0], vq[1], vq[2], vq[3]);
      V4[tok * 2 + 1] = make_float4(vq[4], vq[5], 0.f, 0.f);
    }
  }
}

// ---------------------------------------------------------------------------
// Kernel 2: fused swap-test attention — BARRIER-FREE K-loop.
//  r6: keys are read straight from global (Bk = 2 MB, L2-resident); only V is
//  staged to LDS (16 KB, once, single barrier). With no per-chunk
//  __syncthreads, the compiler can pipeline global loads with vmcnt(N)
//  across iterations (the structure the 2-barrier chunk loop forbids).
//  r4/r5 evidence: chunked-LDS version stuck at ~40% no-issue cycles,
//  IPW16 regressed (overhead amortization), so IPW=32 here.
// MFMA 16x16x32 bf16 layouts:
//   A: row = lane&15, k = (lane>>4)*8 + j
//   B: col = lane&15, k = (lane>>4)*8 + j
//   D: col = lane&15, row = (lane>>4)*4 + reg
// ---------------------------------------------------------------------------
__global__ __launch_bounds__(256, 2) void attn_kernel(
    const uint4* __restrict__ Are, const uint4* __restrict__ Bk,
    const float4* __restrict__ V4, float* __restrict__ part)
{
  __shared__ float4 vbuf[JSLICE * 2];   // 512 keys x 32B = 16 KB

  const int tid  = threadIdx.x;
  const int lane = tid & 63;
  const int wave = tid >> 6;
  const int col  = lane & 15;
  const int quad = lane >> 4;

  const int ib = blockIdx.x & (NBI - 1);
  const int js = blockIdx.x / NBI;
  const int ibase = ib * IPB + wave * IPW;
  const int jbase = js * JSLICE;

  // stage V once (coalesced): 1024 float4 by 256 threads
#pragma unroll
  for (int r = 0; r < 4; ++r)
    vbuf[r * 256 + tid] = V4[jbase * 2 + r * 256 + tid];

  // A fragments for this wave's 32 rows, kept in registers for the whole sweep.
  // aIm derived in-register: (qr,qi) -> (qi,-qr) per packed u32.
  bf16x8 aRe[2][4], aIm[2][4];
#pragma unroll
  for (int rt = 0; rt < 2; ++rt) {
    const int row = ibase + rt * 16 + col;
    const uint4* pr = Are + row * 16 + quad;   // row = 16 uint4 (256B)
#pragma unroll
    for (int s = 0; s < 4; ++s) {
      const uint4 u = pr[s * 4];
      uint4 w;
      w.x = ((u.x << 16) | (u.x >> 16)) ^ 0x80000000u;
      w.y = ((u.y << 16) | (u.y >> 16)) ^ 0x80000000u;
      w.z = ((u.z << 16) | (u.z >> 16)) ^ 0x80000000u;
      w.w = ((u.w << 16) | (u.w >> 16)) ^ 0x80000000u;
      aRe[rt][s] = __builtin_bit_cast(bf16x8, u);
      aIm[rt][s] = __builtin_bit_cast(bf16x8, w);
    }
  }

  float den[8];
  float num[8][6];
#pragma unroll
  for (int r = 0; r < 8; ++r) {
    den[r] = 0.f;
#pragma unroll
    for (int q = 0; q < 6; ++q) num[r][q] = 0.f;
  }

  __syncthreads();   // vbuf ready; the ONLY barrier in this kernel

  // barrier-free K-loop: 32 tiles of 16 keys
#pragma unroll 2
  for (int ct = 0; ct < NCT; ++ct) {
    const int key  = jbase + ct * 16 + col;      // this lane's key column
    const uint4* bp = Bk + key * 16 + quad;      // key row = 16 uint4 (256B)
    bf16x8 bfr[4];
#pragma unroll
    for (int s = 0; s < 4; ++s)
      bfr[s] = __builtin_bit_cast(bf16x8, bp[s * 4]);

    const int keyl = ct * 16 + col;              // local V index (broadcast read)
    const float4 v01 = vbuf[keyl * 2 + 0];
    const float4 v23 = vbuf[keyl * 2 + 1];
    const float vv[6] = {v01.x, v01.y, v01.z, v01.w, v23.x, v23.y};

#pragma unroll
    for (int rt = 0; rt < 2; ++rt) {
      f32x4 aR = {0.f, 0.f, 0.f, 0.f};
      f32x4 aI = {0.f, 0.f, 0.f, 0.f};
#pragma unroll
      for (int s = 0; s < 4; ++s) {
        aR = __builtin_amdgcn_mfma_f32_16x16x32_bf16(aRe[rt][s], bfr[s], aR, 0, 0, 0);
        aI = __builtin_amdgcn_mfma_f32_16x16x32_bf16(aIm[rt][s], bfr[s], aI, 0, 0, 0);
      }
#pragma unroll
      for (int r = 0; r < 4; ++r) {
        const float f = aR[r] * aR[r] + aI[r] * aI[r];
        const float w = __expf(f);               // f in [0,1] -> no max-shift
        const int rr = rt * 4 + r;
        den[rr] += w;
#pragma unroll
        for (int q = 0; q < 6; ++q) num[rr][q] = fmaf(w, vv[q], num[rr][q]);
      }
    }
  }

  // reduce across the 16 lanes (same rows, different cols) of each quad-group
#pragma unroll
  for (int rr = 0; rr < 8; ++rr) {
#pragma unroll
    for (int off = 1; off < 16; off <<= 1) {
      den[rr] += __shfl_xor(den[rr], off, 64);
#pragma unroll
      for (int q = 0; q < 6; ++q) num[rr][q] += __shfl_xor(num[rr][q], off, 64);
    }
  }

  if (col == 0) {
#pragma unroll
    for (int rt = 0; rt < 2; ++rt) {
#pragma unroll
      for (int r = 0; r < 4; ++r) {
        const int row = ibase + rt * 16 + quad * 4 + r;
        // part layout: [row][js][8] -> combine reads are fully coalesced
        float* p = part + ((size_t)(row * JSPLIT + js)) * 8;
        const int rr = rt * 4 + r;
#pragma unroll
        for (int q = 0; q < 6; ++q) p[q] = num[rr][q];
        p[6] = den[rr];
      }
    }
  }
}

// ---------------------------------------------------------------------------
// Kernel 3: combine 16 j-slice partials per row. 8 lanes per row, each lane
// handles 2 slices (coalesced float4 reads), 3-round butterfly, lane0 writes.
// ---------------------------------------------------------------------------
__global__ __launch_bounds__(256) void combine_kernel(
    const float4* __restrict__ part4, float* __restrict__ out)
{
  const int tid = threadIdx.x;
  const int row = blockIdx.x * 32 + (tid >> 3);
  const int sub = tid & 7;

  float acc[7] = {0.f, 0.f, 0.f, 0.f, 0.f, 0.f, 0.f};
#pragma unroll
  for (int h = 0; h < 2; ++h) {
    const int js = sub + h * 8;
    const float4 a0 = part4[(row * JSPLIT + js) * 2 + 0];
    const float4 a1 = part4[(row * JSPLIT + js) * 2 + 1];
    acc[0] += a0.x; acc[1] += a0.y; acc[2] += a0.z; acc[3] += a0.w;
    acc[4] += a1.x; acc[5] += a1.y; acc[6] += a1.z;   // a1.w = unused slot
  }
#pragma unroll
  for (int off = 1; off < 8; off <<= 1) {
#pragma unroll
    for (int q = 0; q < 7; ++q) acc[q] += __shfl_xor(acc[q], off, 64);
  }
  if (sub == 0) {
    const float inv = 1.0f / acc[6];
#pragma unroll
    for (int q = 0; q < 6; ++q) out[row * 6 + q] = acc[q] * inv;
  }
}

// ---------------------------------------------------------------------------
// Workspace layout (bytes):
//   Are  @ 0        : 8192*64*4 = 2 MiB   (bf16 pairs packed in u32)
//   Bk   @ 2 MiB    : 2 MiB
//   V    @ 4 MiB    : 8192*8*4 = 256 KiB  (fp32, padded to 8)
//   part @ 4.25 MiB : 8192*16*8*4 = 4 MiB  ([row][js][8])
//   total 8.25 MiB
// ---------------------------------------------------------------------------
extern "C" void kernel_launch(void* const* d_in, const int* in_sizes, int n_in,
                              void* d_out, int out_size, void* d_ws, size_t ws_size,
                              hipStream_t stream) {
  const float* x  = (const float*)d_in[0];
  const float* pq = (const float*)d_in[1];
  const float* pk = (const float*)d_in[2];
  const float* pv = (const float*)d_in[3];
  char* ws = (char*)d_ws;
  unsigned int* Are = (unsigned int*)(ws);
  unsigned int* Bk  = (unsigned int*)(ws + (size_t)(2u << 20));
  float*        V   = (float*)(ws + (size_t)(4u << 20));
  float*        prt = (float*)(ws + (size_t)(4u << 20) + (size_t)(256u << 10));

  prep_kernel<<<(NT * 3) / 4, 256, 0, stream>>>(x, pq, pk, pv, Are, Bk, (float4*)V);
  attn_kernel<<<NBI * JSPLIT, 256, 0, stream>>>((const uint4*)Are, (const uint4*)Bk,
                                                (const float4*)V, prt);
  combine_kernel<<<NT / 32, 256, 0, stream>>>((const float4*)prt, (float*)d_out);
}